// Round 1
// baseline (419.591 us; speedup 1.0000x reference)
//
#include <hip/hip_runtime.h>

// LookupAttention: B=1,H=12,N=2048,D=64, T=8 tables, S=256 buckets, C=8 bits, KQ=KV=4
#define BH   12
#define NN   2048
#define DD   64
#define TT   8
#define SS   256
#define CC   8
#define KK   4

__device__ __forceinline__ float wave_sum(float v) {
#pragma unroll
  for (int off = 32; off >= 1; off >>= 1) v += __shfl_xor(v, off);
  return v;  // all 64 lanes hold the sum
}

// wave-wide argmax; ties -> smaller index (matches jax.lax.top_k)
__device__ __forceinline__ void wave_argmax(float& val, int& idx) {
#pragma unroll
  for (int off = 32; off >= 1; off >>= 1) {
    float ov = __shfl_xor(val, off);
    int   oi = __shfl_xor(idx, off);
    if (ov > val || (ov == val && oi < idx)) { val = ov; idx = oi; }
  }
}

// Compute the 8 sigmoid bits for (h,t) given per-lane row element xd (lane = d),
// then each lane's 4 bucket products (buckets j = lane*4 + i).
// Product order matches JAX: w = ((1*f0)*f1)*...*f7, f_c = p_c or (1-p_c), bit c of j <-> p_c.
__device__ __forceinline__ void bucket_products(float xd, const float* __restrict__ pr,
                                                int lane, float cv[4], int ci[4]) {
  float p[CC];
#pragma unroll
  for (int c = 0; c < CC; ++c) {
    float s = wave_sum(xd * pr[c * DD + lane]);
    p[c] = 1.0f / (1.0f + expf(-s));
  }
#pragma unroll
  for (int i = 0; i < 4; ++i) {
    int j = lane * 4 + i;
    float w = 1.0f;
#pragma unroll
    for (int c = 0; c < CC; ++c) w *= ((j >> c) & 1) ? p[c] : (1.0f - p[c]);
    cv[i] = w; ci[i] = j;
  }
}

// Pass 1: scatter w_q * v into tables[h][t][bucket][d]
__global__ void build_tables(const float* __restrict__ q,
                             const float* __restrict__ v,
                             const float* __restrict__ mask,
                             const float* __restrict__ proj,
                             float* __restrict__ tables) {
  int gtid = blockIdx.x * blockDim.x + threadIdx.x;
  int wave = gtid >> 6;
  int lane = gtid & 63;
  if (wave >= BH * NN) return;
  int h = wave / NN;
  int n = wave - h * NN;

  float qd = q[((size_t)h * NN + n) * DD + lane];
  float vd = v[((size_t)h * NN + n) * DD + lane] * mask[n];
  float* tbl_h = tables + (size_t)h * TT * SS * DD;

  for (int t = 0; t < TT; ++t) {
    const float* pr = proj + ((size_t)(h * TT + t) * CC) * DD;
    float cv[4]; int ci[4];
    bucket_products(qd, pr, lane, cv, ci);
#pragma unroll
    for (int k = 0; k < KK; ++k) {
      // local best (ties -> smaller index)
      float bv = cv[0]; int bi = ci[0];
#pragma unroll
      for (int i = 1; i < 4; ++i)
        if (cv[i] > bv || (cv[i] == bv && ci[i] < bi)) { bv = cv[i]; bi = ci[i]; }
      float gv = bv; int gi = bi;
      wave_argmax(gv, gi);
      atomicAdd(&tbl_h[((size_t)t * SS + gi) * DD + lane], gv * vd);
      if ((gi >> 2) == lane) cv[gi & 3] = -1.0f;  // remove winner from its owner lane
    }
  }
}

// Pass 2: gather with key-hash top-4, sum over (t,k), /T
__global__ void gather_out(const float* __restrict__ kx,
                           const float* __restrict__ proj,
                           const float* __restrict__ tables,
                           float* __restrict__ out) {
  int gtid = blockIdx.x * blockDim.x + threadIdx.x;
  int wave = gtid >> 6;
  int lane = gtid & 63;
  if (wave >= BH * NN) return;
  int h = wave / NN;
  int n = wave - h * NN;

  float kd = kx[((size_t)h * NN + n) * DD + lane];
  const float* tbl_h = tables + (size_t)h * TT * SS * DD;
  float acc = 0.0f;

  for (int t = 0; t < TT; ++t) {
    const float* pr = proj + ((size_t)(h * TT + t) * CC) * DD;
    float cv[4]; int ci[4];
    bucket_products(kd, pr, lane, cv, ci);
#pragma unroll
    for (int k = 0; k < KK; ++k) {
      float bv = cv[0]; int bi = ci[0];
#pragma unroll
      for (int i = 1; i < 4; ++i)
        if (cv[i] > bv || (cv[i] == bv && ci[i] < bi)) { bv = cv[i]; bi = ci[i]; }
      float gv = bv; int gi = bi;
      wave_argmax(gv, gi);
      acc += gv * tbl_h[((size_t)t * SS + gi) * DD + lane];
      if ((gi >> 2) == lane) cv[gi & 3] = -1.0f;
    }
  }
  out[((size_t)h * NN + n) * DD + lane] = acc * (1.0f / (float)TT);
}

extern "C" void kernel_launch(void* const* d_in, const int* in_sizes, int n_in,
                              void* d_out, int out_size, void* d_ws, size_t ws_size,
                              hipStream_t stream) {
  const float* q    = (const float*)d_in[0];
  const float* k    = (const float*)d_in[1];
  const float* v    = (const float*)d_in[2];
  const float* mask = (const float*)d_in[3];
  const float* proj = (const float*)d_in[4];
  float* out    = (float*)d_out;
  float* tables = (float*)d_ws;

  const size_t tbytes = (size_t)BH * TT * SS * DD * sizeof(float);  // 6 MB
  hipMemsetAsync(d_ws, 0, tbytes, stream);

  dim3 blk(256);
  dim3 grid((BH * NN * 64) / 256);  // one wave per (h,n) row
  build_tables<<<grid, blk, 0, stream>>>(q, v, mask, proj, tables);
  gather_out<<<grid, blk, 0, stream>>>(k, proj, tables, out);
}